// Round 7
// baseline (123.177 us; speedup 1.0000x reference)
//
#include <hip/hip_runtime.h>
#include <stdint.h>

// TrajectoryFK: L=65536 timesteps, J=22 joints, 6D-rotation inputs (fp32).
// Output: (L, 22, 3) fp32 joint positions.
// Serial dependency = affine scan (R,p) <- (R @ d_t, p + R @ (d_t v_t));
// element T_t = (d_t, d_t v_t); compose(P,T) = (P.A T.A, P.b + P.A T.b).
// R7: ONE kernel. Block aggregates published via release-flag; all 256
// blocks co-resident (launch_bounds(256,2) => >=2 blocks/CU capacity), spin
// on flags, redundant aggregate scan per block (12 KB, L2-hot). Tree phase:
// all 15 joint-rot rows preloaded to regs (one latency wait, not 15) and
// positions stored DIRECTLY to global (R6's ov[66] spilled to scratch at
// VGPR=68 - that round-trip was a main cost suspect).

#define LTOT 65536
#define ROW 132                 // 22 joints * 6 floats per timestep (528 B)
#define P1B 256                 // timesteps per block
#define NBLK (LTOT / P1B)       // 256 blocks

struct Aff { float A[9]; float b[3]; };

__device__ __forceinline__ void d6_to_mat(float a0, float a1, float a2,
                                          float a3, float a4, float a5,
                                          float R[9]) {
  // Gram-Schmidt; columns of R are b1,b2,b3 (row-major R[r*3+c]).
  float n1 = sqrtf(a0 * a0 + a1 * a1 + a2 * a2);
  float i1 = 1.0f / fmaxf(n1, 1e-12f);
  float b10 = a0 * i1, b11 = a1 * i1, b12 = a2 * i1;
  float d = b10 * a3 + b11 * a4 + b12 * a5;
  float c0 = a3 - d * b10, c1 = a4 - d * b11, c2 = a5 - d * b12;
  float n2 = sqrtf(c0 * c0 + c1 * c1 + c2 * c2);
  float i2 = 1.0f / fmaxf(n2, 1e-12f);
  float b20 = c0 * i2, b21 = c1 * i2, b22 = c2 * i2;
  float b30 = b11 * b22 - b12 * b21;
  float b31 = b12 * b20 - b10 * b22;
  float b32 = b10 * b21 - b11 * b20;
  R[0] = b10; R[1] = b20; R[2] = b30;
  R[3] = b11; R[4] = b21; R[5] = b31;
  R[6] = b12; R[7] = b22; R[8] = b32;
}

__device__ __forceinline__ void mat_mul(const float A[9], const float B[9], float C[9]) {
#pragma unroll
  for (int i = 0; i < 3; ++i)
#pragma unroll
    for (int j = 0; j < 3; ++j)
      C[i * 3 + j] = A[i * 3 + 0] * B[0 + j] + A[i * 3 + 1] * B[3 + j] + A[i * 3 + 2] * B[6 + j];
}

__device__ __forceinline__ void mat_vec(const float A[9], float x, float y, float z,
                                        float& ox, float& oy, float& oz) {
  ox = A[0] * x + A[1] * y + A[2] * z;
  oy = A[3] * x + A[4] * y + A[5] * z;
  oz = A[6] * x + A[7] * y + A[8] * z;
}

__device__ __forceinline__ void compose(const Aff& P, const Aff& T, Aff& O) {
  mat_mul(P.A, T.A, O.A);
  float bx, by, bz;
  mat_vec(P.A, T.b[0], T.b[1], T.b[2], bx, by, bz);
  O.b[0] = P.b[0] + bx; O.b[1] = P.b[1] + by; O.b[2] = P.b[2] + bz;
}

__device__ __forceinline__ void aff_identity(Aff& v) {
  v.A[0] = 1.f; v.A[1] = 0.f; v.A[2] = 0.f;
  v.A[3] = 0.f; v.A[4] = 1.f; v.A[5] = 0.f;
  v.A[6] = 0.f; v.A[7] = 0.f; v.A[8] = 1.f;
  v.b[0] = 0.f; v.b[1] = 0.f; v.b[2] = 0.f;
}

// Inclusive Hillis-Steele scan across the 64-lane wave.
__device__ __forceinline__ void wave_scan(Aff& v, int lane) {
#pragma unroll
  for (int s = 1; s < 64; s <<= 1) {
    Aff u;
#pragma unroll
    for (int k = 0; k < 9; ++k) u.A[k] = __shfl_up(v.A[k], s, 64);
#pragma unroll
    for (int k = 0; k < 3; ++k) u.b[k] = __shfl_up(v.b[k], s, 64);
    if (lane >= s) { Aff t; compose(u, v, t); v = t; }
  }
}

// Block-local scan: wave scan + cross-wave LDS compose -> inclusive prefix f.
__device__ __forceinline__ void block_scan(Aff& v, int lane, int wid,
                                           float (*sagg)[12], Aff& f) {
  wave_scan(v, lane);
  if (lane == 63) {
#pragma unroll
    for (int k = 0; k < 9; ++k) sagg[wid][k] = v.A[k];
#pragma unroll
    for (int k = 0; k < 3; ++k) sagg[wid][9 + k] = v.b[k];
  }
  __syncthreads();
  Aff pre; aff_identity(pre);
  for (int w = 0; w < wid; ++w) {   // <=3 compositions, broadcast LDS reads
    Aff g, t2;
#pragma unroll
    for (int k = 0; k < 9; ++k) g.A[k] = sagg[w][k];
#pragma unroll
    for (int k = 0; k < 3; ++k) g.b[k] = sagg[w][9 + k];
    compose(pre, g, t2); pre = t2;
  }
  compose(pre, v, f);
}

__global__ __launch_bounds__(P1B, 2) void fk_one(const float* __restrict__ pred,
                                                 const float* __restrict__ offs,
                                                 float* __restrict__ agg,
                                                 int* __restrict__ flags,
                                                 float* __restrict__ out) {
  int tid = threadIdx.x, b = blockIdx.x;
  int t = b * P1B + tid;
  int lane = tid & 63, wid = tid >> 6;

  __shared__ float sagg1[P1B / 64][12];
  __shared__ float sagg2[P1B / 64][12];
  __shared__ float sincl[NBLK][13];   // +1 pad kills write bank conflicts

  // ---- element transform + block-local scan ----
  const float4* q4 = (const float4*)(pred + (size_t)t * ROW);  // 16B-aligned
  float4 qa = q4[0];   // j0: v0 v1 v2 .
  float4 qb = q4[1];   // . . e0 e1
  float4 qc = q4[2];   // e2 e3 e4 e5
  Aff v;
  d6_to_mat(qb.z, qb.w, qc.x, qc.y, qc.z, qc.w, v.A);          // d_t
  mat_vec(v.A, qa.x, qa.y, qa.z, v.b[0], v.b[1], v.b[2]);      // d_t @ v_t
  Aff f;
  block_scan(v, lane, wid, sagg1, f);   // block-local inclusive prefix

  // ---- publish block aggregate (48 B) with release flag ----
  if (tid == P1B - 1) {
    float4* a = (float4*)(agg + (size_t)b * 12);
    a[0] = make_float4(f.A[0], f.A[1], f.A[2], f.A[3]);
    a[1] = make_float4(f.A[4], f.A[5], f.A[6], f.A[7]);
    a[2] = make_float4(f.A[8], f.b[0], f.b[1], f.b[2]);
    __threadfence();
    __hip_atomic_store(&flags[b], 1, __ATOMIC_RELEASE, __HIP_MEMORY_SCOPE_AGENT);
  }

  // ---- wait for all 256 aggregates (all blocks co-resident; no deadlock) --
  while (__hip_atomic_load(&flags[tid], __ATOMIC_ACQUIRE,
                           __HIP_MEMORY_SCOPE_AGENT) != 1) {
    __builtin_amdgcn_s_sleep(2);
  }
  __syncthreads();

  // ---- redundant per-block scan of the 256 aggregates ----
  Aff v2;
  {
    const float4* a = (const float4*)(agg + (size_t)tid * 12);
    float4 a0 = a[0], a1 = a[1], a2 = a[2];
    v2.A[0] = a0.x; v2.A[1] = a0.y; v2.A[2] = a0.z; v2.A[3] = a0.w;
    v2.A[4] = a1.x; v2.A[5] = a1.y; v2.A[6] = a1.z; v2.A[7] = a1.w;
    v2.A[8] = a2.x; v2.b[0] = a2.y; v2.b[1] = a2.z; v2.b[2] = a2.w;
  }
  Aff incl;
  block_scan(v2, lane, wid, sagg2, incl);
#pragma unroll
  for (int k = 0; k < 9; ++k) sincl[tid][k] = incl.A[k];
#pragma unroll
  for (int k = 0; k < 3; ++k) sincl[tid][9 + k] = incl.b[k];
  __syncthreads();

  Aff eb;                     // exclusive prefix for THIS block
  if (b == 0) {
    aff_identity(eb);
  } else {
    const float* sp = sincl[b - 1];   // broadcast read
#pragma unroll
    for (int k = 0; k < 9; ++k) eb.A[k] = sp[k];
#pragma unroll
    for (int k = 0; k < 3; ++k) eb.b[k] = sp[9 + k];
  }

  Aff g;                      // global prefix for timestep t
  compose(eb, f, g);
  const float* R = g.A;       // global R[t]

  // ---- preload ALL 15 joint-rot rows (one batched latency wait) ----
  // slot map: 2->0 3->1 4->2 5->3 6->4 7->5 8->6 9->7 12->8 13->9 14->10
  //           16->11 17->12 18->13 19->14
  const float* q = pred + (size_t)t * ROW;
  float2 Mv[15][3];
#define LOADM(slot, j)                                                         \
  { const float2* qq = (const float2*)(q + (j) * 6);                           \
    Mv[slot][0] = qq[0]; Mv[slot][1] = qq[1]; Mv[slot][2] = qq[2]; }
  LOADM(0, 2)  LOADM(1, 3)  LOADM(2, 4)  LOADM(3, 5)  LOADM(4, 6)
  LOADM(5, 7)  LOADM(6, 8)  LOADM(7, 9)  LOADM(8, 12) LOADM(9, 13)
  LOADM(10, 14) LOADM(11, 16) LOADM(12, 17) LOADM(13, 18) LOADM(14, 19)
#undef LOADM

  float* ob = out + (size_t)t * 66;
#define ST(j, x, y, z) { ob[(j)*3] = x; ob[(j)*3 + 1] = y; ob[(j)*3 + 2] = z; }
#define ROTJ(slot, Rp, Rj)                                                     \
  { float Mx[9];                                                               \
    d6_to_mat(Mv[slot][0].x, Mv[slot][0].y, Mv[slot][1].x, Mv[slot][1].y,      \
              Mv[slot][2].x, Mv[slot][2].y, Mx);                               \
    mat_mul(Rp, Mx, Rj); }
#define CHILD(j, px, py, pz, Rp, ox, oy, oz)                                   \
  { float dx, dy, dz;                                                          \
    mat_vec(Rp, offs[(j)*3], offs[(j)*3 + 1], offs[(j)*3 + 2], dx, dy, dz);    \
    ox = px + dx; oy = py + dy; oz = pz + dz; ST(j, ox, oy, oz) }

  float p0x = g.b[0], p0y = g.b[1], p0z = g.b[2];
  ST(0, p0x, p0y, p0z)
  float p1x, p1y, p1z, p2x, p2y, p2z, p3x, p3y, p3z, p4x, p4y, p4z;
  CHILD(1, p0x, p0y, p0z, R, p1x, p1y, p1z)     // rots[1] = R
  CHILD(2, p0x, p0y, p0z, R, p2x, p2y, p2z)
  CHILD(3, p0x, p0y, p0z, R, p3x, p3y, p3z)
  CHILD(4, p1x, p1y, p1z, R, p4x, p4y, p4z)     // parent 1, rots[1] = R
  float r2[9], r3[9], r4[9];
  ROTJ(0, R, r2) ROTJ(1, R, r3) ROTJ(2, R, r4)
  float p5x, p5y, p5z, p6x, p6y, p6z, p7x, p7y, p7z;
  CHILD(5, p2x, p2y, p2z, r2, p5x, p5y, p5z)
  CHILD(6, p3x, p3y, p3z, r3, p6x, p6y, p6z)
  CHILD(7, p4x, p4y, p4z, r4, p7x, p7y, p7z)
  float r5[9], r6[9], r7[9];
  ROTJ(3, r2, r5) ROTJ(4, r3, r6) ROTJ(5, r4, r7)
  float p8x, p8y, p8z, p9x, p9y, p9z, p10x, p10y, p10z;
  CHILD(8, p5x, p5y, p5z, r5, p8x, p8y, p8z)
  CHILD(9, p6x, p6y, p6z, r6, p9x, p9y, p9z)
  CHILD(10, p7x, p7y, p7z, r7, p10x, p10y, p10z)   // leaf
  float r8[9], r9[9];
  ROTJ(6, r5, r8) ROTJ(7, r6, r9)
  float p11x, p11y, p11z;
  CHILD(11, p8x, p8y, p8z, r8, p11x, p11y, p11z)   // leaf
  float p12x, p12y, p12z, p13x, p13y, p13z, p14x, p14y, p14z;
  CHILD(12, p9x, p9y, p9z, r9, p12x, p12y, p12z)
  CHILD(13, p9x, p9y, p9z, r9, p13x, p13y, p13z)
  CHILD(14, p9x, p9y, p9z, r9, p14x, p14y, p14z)
  float r12[9], r13[9], r14[9];
  ROTJ(8, r9, r12) ROTJ(9, r9, r13) ROTJ(10, r9, r14)
  float p15x, p15y, p15z, p16x, p16y, p16z, p17x, p17y, p17z;
  CHILD(15, p12x, p12y, p12z, r12, p15x, p15y, p15z)  // leaf
  CHILD(16, p13x, p13y, p13z, r13, p16x, p16y, p16z)
  CHILD(17, p14x, p14y, p14z, r14, p17x, p17y, p17z)
  float r16[9], r17[9];
  ROTJ(11, r13, r16) ROTJ(12, r14, r17)
  float p18x, p18y, p18z, p19x, p19y, p19z;
  CHILD(18, p16x, p16y, p16z, r16, p18x, p18y, p18z)
  CHILD(19, p17x, p17y, p17z, r17, p19x, p19y, p19z)
  float r18[9], r19[9];
  ROTJ(13, r16, r18) ROTJ(14, r17, r19)
  float p20x, p20y, p20z, p21x, p21y, p21z;
  CHILD(20, p18x, p18y, p18z, r18, p20x, p20y, p20z)  // leaf
  CHILD(21, p19x, p19y, p19z, r19, p21x, p21y, p21z)  // leaf
#undef CHILD
#undef ROTJ
#undef ST
}

extern "C" void kernel_launch(void* const* d_in, const int* in_sizes, int n_in,
                              void* d_out, int out_size, void* d_ws, size_t ws_size,
                              hipStream_t stream) {
  const float* pred = (const float*)d_in[0];   // (L, 22, 6) fp32
  const float* offs = (const float*)d_in[1];   // (22, 3)    fp32
  float* out = (float*)d_out;                  // (L, 22, 3) fp32
  float* agg = (float*)d_ws;                   // 12 * NBLK floats
  int* flags = (int*)((char*)d_ws + 16384);    // 256 ints, separate lines

  hipMemsetAsync(flags, 0, NBLK * sizeof(int), stream);  // capture-legal
  fk_one<<<NBLK, P1B, 0, stream>>>(pred, offs, agg, flags, out);
}

// Round 8
// 105.523 us; speedup vs baseline: 1.1673x; 1.1673x over previous
//
#include <hip/hip_runtime.h>
#include <stdint.h>

// TrajectoryFK: L=65536, J=22. R8: occupancy-shaped pipeline.
// R4-R7 evidence: every kernel shaped 65536 threads = 1024 waves = 4 waves/CU
// (1 wave/SIMD) is HBM-LATENCY-bound (~800 GB/s, OccupancyPercent ~9%).
// Only the scan needs that shape. The tree (70% of traffic) is split 5
// chain-threads per t -> block (64,5), 1024 blocks, 20 waves/CU; each wave
// is one chain type for 64 consecutive t (no divergence); <=6 independent
// row loads per thread, small live state (no spill).

#define LTOT 65536
#define ROW 132                 // 22 joints * 6 floats per timestep (528 B)
#define P1B 256                 // timesteps per scan block
#define NSCB (LTOT / P1B)       // 256 scan blocks

struct Aff { float A[9]; float b[3]; };

__device__ __forceinline__ void d6_to_mat(float a0, float a1, float a2,
                                          float a3, float a4, float a5,
                                          float R[9]) {
  // Gram-Schmidt; columns of R are b1,b2,b3 (row-major R[r*3+c]).
  float n1 = sqrtf(a0 * a0 + a1 * a1 + a2 * a2);
  float i1 = 1.0f / fmaxf(n1, 1e-12f);
  float b10 = a0 * i1, b11 = a1 * i1, b12 = a2 * i1;
  float d = b10 * a3 + b11 * a4 + b12 * a5;
  float c0 = a3 - d * b10, c1 = a4 - d * b11, c2 = a5 - d * b12;
  float n2 = sqrtf(c0 * c0 + c1 * c1 + c2 * c2);
  float i2 = 1.0f / fmaxf(n2, 1e-12f);
  float b20 = c0 * i2, b21 = c1 * i2, b22 = c2 * i2;
  float b30 = b11 * b22 - b12 * b21;
  float b31 = b12 * b20 - b10 * b22;
  float b32 = b10 * b21 - b11 * b20;
  R[0] = b10; R[1] = b20; R[2] = b30;
  R[3] = b11; R[4] = b21; R[5] = b31;
  R[6] = b12; R[7] = b22; R[8] = b32;
}

__device__ __forceinline__ void mat_mul(const float A[9], const float B[9], float C[9]) {
#pragma unroll
  for (int i = 0; i < 3; ++i)
#pragma unroll
    for (int j = 0; j < 3; ++j)
      C[i * 3 + j] = A[i * 3 + 0] * B[0 + j] + A[i * 3 + 1] * B[3 + j] + A[i * 3 + 2] * B[6 + j];
}

__device__ __forceinline__ void mat_vec(const float A[9], float x, float y, float z,
                                        float& ox, float& oy, float& oz) {
  ox = A[0] * x + A[1] * y + A[2] * z;
  oy = A[3] * x + A[4] * y + A[5] * z;
  oz = A[6] * x + A[7] * y + A[8] * z;
}

__device__ __forceinline__ void compose(const Aff& P, const Aff& T, Aff& O) {
  mat_mul(P.A, T.A, O.A);
  float bx, by, bz;
  mat_vec(P.A, T.b[0], T.b[1], T.b[2], bx, by, bz);
  O.b[0] = P.b[0] + bx; O.b[1] = P.b[1] + by; O.b[2] = P.b[2] + bz;
}

__device__ __forceinline__ void aff_identity(Aff& v) {
  v.A[0] = 1.f; v.A[1] = 0.f; v.A[2] = 0.f;
  v.A[3] = 0.f; v.A[4] = 1.f; v.A[5] = 0.f;
  v.A[6] = 0.f; v.A[7] = 0.f; v.A[8] = 1.f;
  v.b[0] = 0.f; v.b[1] = 0.f; v.b[2] = 0.f;
}

__device__ __forceinline__ void wave_scan(Aff& v, int lane) {
#pragma unroll
  for (int s = 1; s < 64; s <<= 1) {
    Aff u;
#pragma unroll
    for (int k = 0; k < 9; ++k) u.A[k] = __shfl_up(v.A[k], s, 64);
#pragma unroll
    for (int k = 0; k < 3; ++k) u.b[k] = __shfl_up(v.b[k], s, 64);
    if (lane >= s) { Aff t; compose(u, v, t); v = t; }
  }
}

__device__ __forceinline__ void block_scan(Aff& v, int lane, int wid,
                                           float (*sagg)[12], Aff& f) {
  wave_scan(v, lane);
  if (lane == 63) {
#pragma unroll
    for (int k = 0; k < 9; ++k) sagg[wid][k] = v.A[k];
#pragma unroll
    for (int k = 0; k < 3; ++k) sagg[wid][9 + k] = v.b[k];
  }
  __syncthreads();
  Aff pre; aff_identity(pre);
  for (int w = 0; w < wid; ++w) {
    Aff g, t2;
#pragma unroll
    for (int k = 0; k < 9; ++k) g.A[k] = sagg[w][k];
#pragma unroll
    for (int k = 0; k < 3; ++k) g.b[k] = sagg[w][9 + k];
    compose(pre, g, t2); pre = t2;
  }
  compose(pre, v, f);
}

// ---------------- K1: block-local scan -> loc + agg (validated R4 shape) --
__global__ __launch_bounds__(P1B) void fk_scan(const float* __restrict__ pred,
                                               float* __restrict__ loc,
                                               float* __restrict__ agg) {
  int tid = threadIdx.x;
  int t = blockIdx.x * P1B + tid;
  int lane = tid & 63, wid = tid >> 6;
  __shared__ float sagg[P1B / 64][12];

  const float4* q4 = (const float4*)(pred + (size_t)t * ROW);
  float4 qa = q4[0];   // j0: v0 v1 v2 .
  float4 qb = q4[1];   // . . e0 e1
  float4 qc = q4[2];   // e2 e3 e4 e5
  Aff v;
  d6_to_mat(qb.z, qb.w, qc.x, qc.y, qc.z, qc.w, v.A);
  mat_vec(v.A, qa.x, qa.y, qa.z, v.b[0], v.b[1], v.b[2]);
  Aff f;
  block_scan(v, lane, wid, sagg, f);

  float4* o = (float4*)(loc + (size_t)t * 12);
  o[0] = make_float4(f.A[0], f.A[1], f.A[2], f.A[3]);
  o[1] = make_float4(f.A[4], f.A[5], f.A[6], f.A[7]);
  o[2] = make_float4(f.A[8], f.b[0], f.b[1], f.b[2]);
  if (tid == P1B - 1) {
    float4* a = (float4*)(agg + (size_t)blockIdx.x * 12);
    a[0] = make_float4(f.A[0], f.A[1], f.A[2], f.A[3]);
    a[1] = make_float4(f.A[4], f.A[5], f.A[6], f.A[7]);
    a[2] = make_float4(f.A[8], f.b[0], f.b[1], f.b[2]);
  }
}

// ---------------- K2: exclusive scan of 256 aggregates (R4-validated) ----
__global__ __launch_bounds__(NSCB) void fk_scan2(const float* __restrict__ agg,
                                                 float* __restrict__ excl) {
  int i = threadIdx.x, lane = i & 63, wid = i >> 6;
  Aff v;
  {
    const float4* a = (const float4*)(agg + (size_t)i * 12);
    float4 a0 = a[0], a1 = a[1], a2 = a[2];
    v.A[0] = a0.x; v.A[1] = a0.y; v.A[2] = a0.z; v.A[3] = a0.w;
    v.A[4] = a1.x; v.A[5] = a1.y; v.A[6] = a1.z; v.A[7] = a1.w;
    v.A[8] = a2.x; v.b[0] = a2.y; v.b[1] = a2.z; v.b[2] = a2.w;
  }
  __shared__ float sagg[NSCB / 64][12];
  Aff f;
  block_scan(v, lane, wid, sagg, f);       // inclusive[i]
  // get wid's cross-wave prefix again for lane 0 (recompute: cheap)
  Aff pre; aff_identity(pre);
  for (int w = 0; w < wid; ++w) {
    Aff g, t2;
#pragma unroll
    for (int k = 0; k < 9; ++k) g.A[k] = sagg[w][k];
#pragma unroll
    for (int k = 0; k < 3; ++k) g.b[k] = sagg[w][9 + k];
    compose(pre, g, t2); pre = t2;
  }
  Aff e;
#pragma unroll
  for (int k = 0; k < 9; ++k) e.A[k] = __shfl_up(f.A[k], 1, 64);
#pragma unroll
  for (int k = 0; k < 3; ++k) e.b[k] = __shfl_up(f.b[k], 1, 64);
  if (lane == 0) e = pre;                  // identity for i==0
  float4* o = (float4*)(excl + (size_t)i * 12);
  o[0] = make_float4(e.A[0], e.A[1], e.A[2], e.A[3]);
  o[1] = make_float4(e.A[4], e.A[5], e.A[6], e.A[7]);
  o[2] = make_float4(e.A[8], e.b[0], e.b[1], e.b[2]);
}

// ---------------- K3: chain-split tree, block (64,5), 20 waves/CU --------
struct Rowv { float2 a, b, c; };
__device__ __forceinline__ Rowv loadrow(const float* q, int j) {
  const float2* p = (const float2*)(q + j * 6);   // 8B-aligned
  Rowv r; r.a = p[0]; r.b = p[1]; r.c = p[2]; return r;
}
__device__ __forceinline__ void rowmat(const Rowv& r, float M[9]) {
  d6_to_mat(r.a.x, r.a.y, r.b.x, r.b.y, r.c.x, r.c.y, M);
}
__device__ __forceinline__ void childp(const float* Rp, const float* offs, int j,
                                       float px, float py, float pz,
                                       float& ox, float& oy, float& oz,
                                       float* ob) {
  float dx, dy, dz;
  mat_vec(Rp, offs[j * 3], offs[j * 3 + 1], offs[j * 3 + 2], dx, dy, dz);
  ox = px + dx; oy = py + dy; oz = pz + dz;
  ob[j * 3] = ox; ob[j * 3 + 1] = oy; ob[j * 3 + 2] = oz;
}

__global__ __launch_bounds__(320, 4) void fk_tree(const float* __restrict__ pred,
                                                  const float* __restrict__ offs,
                                                  const float* __restrict__ loc,
                                                  const float* __restrict__ excl,
                                                  float* __restrict__ out) {
  int lane = threadIdx.x;          // t-offset within the block's 64
  int chain = threadIdx.y;         // 0..4, uniform per wave
  int t = blockIdx.x * 64 + lane;
  int sb = blockIdx.x >> 2;        // scan-block index: block-uniform -> SGPR

  Aff e, l;
  {
    const float4* a = (const float4*)(excl + (size_t)sb * 12);
    float4 a0 = a[0], a1 = a[1], a2 = a[2];
    e.A[0] = a0.x; e.A[1] = a0.y; e.A[2] = a0.z; e.A[3] = a0.w;
    e.A[4] = a1.x; e.A[5] = a1.y; e.A[6] = a1.z; e.A[7] = a1.w;
    e.A[8] = a2.x; e.b[0] = a2.y; e.b[1] = a2.z; e.b[2] = a2.w;
  }
  {
    const float4* a = (const float4*)(loc + (size_t)t * 12);
    float4 a0 = a[0], a1 = a[1], a2 = a[2];
    l.A[0] = a0.x; l.A[1] = a0.y; l.A[2] = a0.z; l.A[3] = a0.w;
    l.A[4] = a1.x; l.A[5] = a1.y; l.A[6] = a1.z; l.A[7] = a1.w;
    l.A[8] = a2.x; l.b[0] = a2.y; l.b[1] = a2.z; l.b[2] = a2.w;
  }
  Aff g;
  compose(e, l, g);                // global (R, root_pos) for timestep t
  const float* R = g.A;
  float px = g.b[0], py = g.b[1], pz = g.b[2];
  const float* q = pred + (size_t)t * ROW;
  float* ob = out + (size_t)t * 66;

  float M[9], ra[9], rb[9];
  if (chain == 0) {                // stores 0,1,4,7,10
    Rowv w4 = loadrow(q, 4), w7 = loadrow(q, 7);
    ob[0] = px; ob[1] = py; ob[2] = pz;
    float p1x, p1y, p1z, p4x, p4y, p4z, p7x, p7y, p7z, dx, dy, dz;
    childp(R, offs, 1, px, py, pz, p1x, p1y, p1z, ob);     // rots[1]=R
    rowmat(w4, M); mat_mul(R, M, ra);                      // r4
    childp(R, offs, 4, p1x, p1y, p1z, p4x, p4y, p4z, ob);  // parent 1, rot R
    childp(ra, offs, 7, p4x, p4y, p4z, p7x, p7y, p7z, ob);
    rowmat(w7, M); mat_mul(ra, M, rb);                     // r7
    childp(rb, offs, 10, p7x, p7y, p7z, dx, dy, dz, ob);
  } else if (chain == 1) {         // stores 2,5,8,11
    Rowv w2 = loadrow(q, 2), w5 = loadrow(q, 5), w8 = loadrow(q, 8);
    float p2x, p2y, p2z, p5x, p5y, p5z, p8x, p8y, p8z, dx, dy, dz;
    childp(R, offs, 2, px, py, pz, p2x, p2y, p2z, ob);
    rowmat(w2, M); mat_mul(R, M, ra);                      // r2
    childp(ra, offs, 5, p2x, p2y, p2z, p5x, p5y, p5z, ob);
    rowmat(w5, M); mat_mul(ra, M, rb);                     // r5
    childp(rb, offs, 8, p5x, p5y, p5z, p8x, p8y, p8z, ob);
    rowmat(w8, M); mat_mul(rb, M, ra);                     // r8
    childp(ra, offs, 11, p8x, p8y, p8z, dx, dy, dz, ob);
  } else if (chain == 2) {         // stores 3,6,9,12,15
    Rowv w3 = loadrow(q, 3), w6 = loadrow(q, 6), w9 = loadrow(q, 9),
         w12 = loadrow(q, 12);
    float p3x, p3y, p3z, p6x, p6y, p6z, p9x, p9y, p9z;
    float p12x, p12y, p12z, dx, dy, dz;
    childp(R, offs, 3, px, py, pz, p3x, p3y, p3z, ob);
    rowmat(w3, M); mat_mul(R, M, ra);                      // r3
    childp(ra, offs, 6, p3x, p3y, p3z, p6x, p6y, p6z, ob);
    rowmat(w6, M); mat_mul(ra, M, rb);                     // r6
    childp(rb, offs, 9, p6x, p6y, p6z, p9x, p9y, p9z, ob);
    rowmat(w9, M); mat_mul(rb, M, ra);                     // r9
    childp(ra, offs, 12, p9x, p9y, p9z, p12x, p12y, p12z, ob);
    rowmat(w12, M); mat_mul(ra, M, rb);                    // r12
    childp(rb, offs, 15, p12x, p12y, p12z, dx, dy, dz, ob);
  } else {                         // chains 3/4: recompute r9,p9 prefix
    int jA = (chain == 3) ? 13 : 14;
    int jB = (chain == 3) ? 16 : 17;
    int jC = (chain == 3) ? 18 : 19;
    int jD = (chain == 3) ? 20 : 21;
    Rowv w3 = loadrow(q, 3), w6 = loadrow(q, 6), w9 = loadrow(q, 9);
    Rowv wA = loadrow(q, jA), wB = loadrow(q, jB), wC = loadrow(q, jC);
    float p3x, p3y, p3z, p6x, p6y, p6z, p9x, p9y, p9z;
    float pAx, pAy, pAz, pBx, pBy, pBz, pCx, pCy, pCz, dx, dy, dz;
    // prefix (not stored)
    mat_vec(R, offs[9], offs[10], offs[11], dx, dy, dz);   // off3
    p3x = px + dx; p3y = py + dy; p3z = pz + dz;
    rowmat(w3, M); mat_mul(R, M, ra);                      // r3
    mat_vec(ra, offs[18], offs[19], offs[20], dx, dy, dz); // off6
    p6x = p3x + dx; p6y = p3y + dy; p6z = p3z + dz;
    rowmat(w6, M); mat_mul(ra, M, rb);                     // r6
    mat_vec(rb, offs[27], offs[28], offs[29], dx, dy, dz); // off9
    p9x = p6x + dx; p9y = p6y + dy; p9z = p6z + dz;
    rowmat(w9, M); mat_mul(rb, M, ra);                     // r9
    // stored chain
    childp(ra, offs, jA, p9x, p9y, p9z, pAx, pAy, pAz, ob);
    rowmat(wA, M); mat_mul(ra, M, rb);                     // rA
    childp(rb, offs, jB, pAx, pAy, pAz, pBx, pBy, pBz, ob);
    rowmat(wB, M); mat_mul(rb, M, ra);                     // rB
    childp(ra, offs, jC, pBx, pBy, pBz, pCx, pCy, pCz, ob);
    rowmat(wC, M); mat_mul(ra, M, rb);                     // rC
    childp(rb, offs, jD, pCx, pCy, pCz, dx, dy, dz, ob);
  }
}

extern "C" void kernel_launch(void* const* d_in, const int* in_sizes, int n_in,
                              void* d_out, int out_size, void* d_ws, size_t ws_size,
                              hipStream_t stream) {
  const float* pred = (const float*)d_in[0];   // (L, 22, 6) fp32
  const float* offs = (const float*)d_in[1];   // (22, 3)    fp32
  float* out = (float*)d_out;                  // (L, 22, 3) fp32

  float* ws = (float*)d_ws;
  float* loc  = ws;                                  // 12 * L floats (3 MB)
  float* agg  = ws + (size_t)12 * LTOT;              // 12 * NSCB
  float* excl = ws + (size_t)12 * LTOT + 12 * NSCB;

  fk_scan<<<NSCB, P1B, 0, stream>>>(pred, loc, agg);
  fk_scan2<<<1, NSCB, 0, stream>>>(agg, excl);
  fk_tree<<<LTOT / 64, dim3(64, 5), 0, stream>>>(pred, offs, loc, excl, out);
}

// Round 9
// 97.446 us; speedup vs baseline: 1.2641x; 1.0829x over previous
//
#include <hip/hip_runtime.h>
#include <stdint.h>

// TrajectoryFK: L=65536, J=22, fp32 in/out.
// R9: TWO kernels, no loc intermediate, high-occupancy tree.
// Ledger from R6-R8: harness reset (ws poison 268MB etc) ~= 60 us fixed;
// R6 (2 launches, loc-free, low-occ tree) = 37 us controllable;
// R8 (3 launches, loc roundtrip, high-occ tree) = 46 us. This round takes
// the best of both: K1 = agg only; K2 = per-256-t block of 1024 threads
// (16 waves/CU): waves z=0 recompute local scan, waves z=1 scan the 256
// aggs concurrently, (R,p) via LDS, then 4-way chain-split tree on all
// 16 waves with rows preloaded before the scan (latency overlap).

#define LTOT 65536
#define ROW 132                 // 22 joints * 6 floats per timestep (528 B)
#define P1B 256                 // timesteps per scan block
#define NSCB (LTOT / P1B)       // 256 scan blocks

struct Aff { float A[9]; float b[3]; };

__device__ __forceinline__ void d6_to_mat(float a0, float a1, float a2,
                                          float a3, float a4, float a5,
                                          float R[9]) {
  // Gram-Schmidt; columns of R are b1,b2,b3 (row-major R[r*3+c]).
  float n1 = sqrtf(a0 * a0 + a1 * a1 + a2 * a2);
  float i1 = 1.0f / fmaxf(n1, 1e-12f);
  float b10 = a0 * i1, b11 = a1 * i1, b12 = a2 * i1;
  float d = b10 * a3 + b11 * a4 + b12 * a5;
  float c0 = a3 - d * b10, c1 = a4 - d * b11, c2 = a5 - d * b12;
  float n2 = sqrtf(c0 * c0 + c1 * c1 + c2 * c2);
  float i2 = 1.0f / fmaxf(n2, 1e-12f);
  float b20 = c0 * i2, b21 = c1 * i2, b22 = c2 * i2;
  float b30 = b11 * b22 - b12 * b21;
  float b31 = b12 * b20 - b10 * b22;
  float b32 = b10 * b21 - b11 * b20;
  R[0] = b10; R[1] = b20; R[2] = b30;
  R[3] = b11; R[4] = b21; R[5] = b31;
  R[6] = b12; R[7] = b22; R[8] = b32;
}

__device__ __forceinline__ void mat_mul(const float A[9], const float B[9], float C[9]) {
#pragma unroll
  for (int i = 0; i < 3; ++i)
#pragma unroll
    for (int j = 0; j < 3; ++j)
      C[i * 3 + j] = A[i * 3 + 0] * B[0 + j] + A[i * 3 + 1] * B[3 + j] + A[i * 3 + 2] * B[6 + j];
}

__device__ __forceinline__ void mat_vec(const float A[9], float x, float y, float z,
                                        float& ox, float& oy, float& oz) {
  ox = A[0] * x + A[1] * y + A[2] * z;
  oy = A[3] * x + A[4] * y + A[5] * z;
  oz = A[6] * x + A[7] * y + A[8] * z;
}

__device__ __forceinline__ void compose(const Aff& P, const Aff& T, Aff& O) {
  mat_mul(P.A, T.A, O.A);
  float bx, by, bz;
  mat_vec(P.A, T.b[0], T.b[1], T.b[2], bx, by, bz);
  O.b[0] = P.b[0] + bx; O.b[1] = P.b[1] + by; O.b[2] = P.b[2] + bz;
}

__device__ __forceinline__ void aff_identity(Aff& v) {
  v.A[0] = 1.f; v.A[1] = 0.f; v.A[2] = 0.f;
  v.A[3] = 0.f; v.A[4] = 1.f; v.A[5] = 0.f;
  v.A[6] = 0.f; v.A[7] = 0.f; v.A[8] = 1.f;
  v.b[0] = 0.f; v.b[1] = 0.f; v.b[2] = 0.f;
}

__device__ __forceinline__ void wave_scan(Aff& v, int lane) {
#pragma unroll
  for (int s = 1; s < 64; s <<= 1) {
    Aff u;
#pragma unroll
    for (int k = 0; k < 9; ++k) u.A[k] = __shfl_up(v.A[k], s, 64);
#pragma unroll
    for (int k = 0; k < 3; ++k) u.b[k] = __shfl_up(v.b[k], s, 64);
    if (lane >= s) { Aff t; compose(u, v, t); v = t; }
  }
}

__device__ __forceinline__ void elem_transform(const float* __restrict__ pred,
                                               int t, Aff& v) {
  const float4* q4 = (const float4*)(pred + (size_t)t * ROW);  // 16B-aligned
  float4 qa = q4[0];   // j0: v0 v1 v2 .
  float4 qb = q4[1];   // . . e0 e1
  float4 qc = q4[2];   // e2 e3 e4 e5
  d6_to_mat(qb.z, qb.w, qc.x, qc.y, qc.z, qc.w, v.A);          // d_t
  mat_vec(v.A, qa.x, qa.y, qa.z, v.b[0], v.b[1], v.b[2]);      // d_t @ v_t
}

// ---------------- K1: 256 block aggregates only (R6-validated) ----------
__global__ __launch_bounds__(P1B) void fk_agg(const float* __restrict__ pred,
                                              float* __restrict__ agg) {
  int tid = threadIdx.x;
  int t = blockIdx.x * P1B + tid;
  int lane = tid & 63, wid = tid >> 6;
  Aff v;
  elem_transform(pred, t, v);
  wave_scan(v, lane);
  __shared__ float sagg[P1B / 64][12];
  if (lane == 63) {
#pragma unroll
    for (int k = 0; k < 9; ++k) sagg[wid][k] = v.A[k];
#pragma unroll
    for (int k = 0; k < 3; ++k) sagg[wid][9 + k] = v.b[k];
  }
  __syncthreads();
  if (tid == P1B - 1) {      // v == inclusive of last wave
    Aff pre; aff_identity(pre);
    for (int w = 0; w < P1B / 64 - 1; ++w) {
      Aff g, t2;
#pragma unroll
      for (int k = 0; k < 9; ++k) g.A[k] = sagg[w][k];
#pragma unroll
      for (int k = 0; k < 3; ++k) g.b[k] = sagg[w][9 + k];
      compose(pre, g, t2); pre = t2;
    }
    Aff f; compose(pre, v, f);
    float4* a = (float4*)(agg + (size_t)blockIdx.x * 12);
    a[0] = make_float4(f.A[0], f.A[1], f.A[2], f.A[3]);
    a[1] = make_float4(f.A[4], f.A[5], f.A[6], f.A[7]);
    a[2] = make_float4(f.A[8], f.b[0], f.b[1], f.b[2]);
  }
}

// ---------------- K2: scan (waves z=0,1) + 4-chain tree, 1024 thr -------
struct Rowv { float2 a, b, c; };
__device__ __forceinline__ Rowv loadrow(const float* q, int j) {
  const float2* p = (const float2*)(q + j * 6);   // 8B-aligned
  Rowv r; r.a = p[0]; r.b = p[1]; r.c = p[2]; return r;
}
__device__ __forceinline__ void rowmat(const Rowv& r, float M[9]) {
  d6_to_mat(r.a.x, r.a.y, r.b.x, r.b.y, r.c.x, r.c.y, M);
}
__device__ __forceinline__ void childp(const float* Rp, const float* offs, int j,
                                       float px, float py, float pz,
                                       float& ox, float& oy, float& oz,
                                       float* ob) {
  float dx, dy, dz;
  mat_vec(Rp, offs[j * 3], offs[j * 3 + 1], offs[j * 3 + 2], dx, dy, dz);
  ox = px + dx; oy = py + dy; oz = pz + dz;
  ob[j * 3] = ox; ob[j * 3 + 1] = oy; ob[j * 3 + 2] = oz;
}

__global__ __launch_bounds__(1024) void fk_main(const float* __restrict__ pred,
                                                const float* __restrict__ offs,
                                                const float* __restrict__ agg,
                                                float* __restrict__ out) {
  int x = threadIdx.x;            // lane in wave = t offset within quarter
  int y = threadIdx.y;            // chain 0..3 (wave-uniform)
  int z = threadIdx.z;            // quarter 0..3 (wave-uniform)
  int b = blockIdx.x;

  __shared__ float sagg1[4][12];
  __shared__ float sagg2[4][12];
  __shared__ float ebuf[12];
  __shared__ float sg[P1B][13];   // per-t global (R,p); stride 13 pad

  int tl = z * 64 + x;            // t offset in this block's 256
  int t = b * P1B + tl;
  const float* q = pred + (size_t)t * ROW;
  float* ob = out + (size_t)t * 66;

  // ---- issue this thread's chain row loads FIRST (overlap with scan) ----
  Rowv w0, w1, w2, w3, w4, w5, w6, w7, w8;
  if (y == 0) {                    // chain 0: needs M4, M7
    w0 = loadrow(q, 4); w1 = loadrow(q, 7);
  } else if (y == 1) {             // chain 1: M2, M5, M8
    w0 = loadrow(q, 2); w1 = loadrow(q, 5); w2 = loadrow(q, 8);
  } else if (y == 2) {             // chain 2: M3, M6, M9, M12
    w0 = loadrow(q, 3); w1 = loadrow(q, 6); w2 = loadrow(q, 9);
    w3 = loadrow(q, 12);
  } else {                         // chain 3: M3,M6,M9 + M13,M16,M18 + M14,M17,M19
    w0 = loadrow(q, 3); w1 = loadrow(q, 6); w2 = loadrow(q, 9);
    w3 = loadrow(q, 13); w4 = loadrow(q, 16); w5 = loadrow(q, 18);
    w6 = loadrow(q, 14); w7 = loadrow(q, 17); w8 = loadrow(q, 19);
  }

  // ---- phase A: concurrent scans on waves z=0 (local) and z=1 (aggs) ----
  int s = x + 64 * y;              // scan index 0..255 within the z-group
  Aff v, f;                        // z==0: local element / inclusive prefix
  Aff v2, incl;                    // z==1: aggregate / inclusive
  if (z == 0) {
    elem_transform(pred, b * P1B + s, v);   // L2-hot (K1 just read these)
    wave_scan(v, x);
    if (x == 63) {
#pragma unroll
      for (int k = 0; k < 9; ++k) sagg1[y][k] = v.A[k];
#pragma unroll
      for (int k = 0; k < 3; ++k) sagg1[y][9 + k] = v.b[k];
    }
  } else if (z == 1) {
    const float4* a = (const float4*)(agg + (size_t)s * 12);
    float4 a0 = a[0], a1 = a[1], a2 = a[2];
    v2.A[0] = a0.x; v2.A[1] = a0.y; v2.A[2] = a0.z; v2.A[3] = a0.w;
    v2.A[4] = a1.x; v2.A[5] = a1.y; v2.A[6] = a1.z; v2.A[7] = a1.w;
    v2.A[8] = a2.x; v2.b[0] = a2.y; v2.b[1] = a2.z; v2.b[2] = a2.w;
    wave_scan(v2, x);
    if (x == 63) {
#pragma unroll
      for (int k = 0; k < 9; ++k) sagg2[y][k] = v2.A[k];
#pragma unroll
      for (int k = 0; k < 3; ++k) sagg2[y][9 + k] = v2.b[k];
    }
  }
  __syncthreads();

  if (z == 0) {
    Aff pre; aff_identity(pre);
    for (int w = 0; w < y; ++w) {
      Aff gg, t2;
#pragma unroll
      for (int k = 0; k < 9; ++k) gg.A[k] = sagg1[w][k];
#pragma unroll
      for (int k = 0; k < 3; ++k) gg.b[k] = sagg1[w][9 + k];
      compose(pre, gg, t2); pre = t2;
    }
    compose(pre, v, f);            // block-local inclusive prefix for t_s
  } else if (z == 1) {
    Aff pre; aff_identity(pre);
    for (int w = 0; w < y; ++w) {
      Aff gg, t2;
#pragma unroll
      for (int k = 0; k < 9; ++k) gg.A[k] = sagg2[w][k];
#pragma unroll
      for (int k = 0; k < 3; ++k) gg.b[k] = sagg2[w][9 + k];
      compose(pre, gg, t2); pre = t2;
    }
    compose(pre, v2, incl);        // inclusive agg scan element s
    if (s == b - 1) {              // only the predecessor element is needed
#pragma unroll
      for (int k = 0; k < 9; ++k) ebuf[k] = incl.A[k];
#pragma unroll
      for (int k = 0; k < 3; ++k) ebuf[9 + k] = incl.b[k];
    }
  }
  __syncthreads();

  if (z == 0) {                    // compose global prefix, publish to LDS
    Aff eb;
    if (b == 0) aff_identity(eb);
    else {
#pragma unroll
      for (int k = 0; k < 9; ++k) eb.A[k] = ebuf[k];
#pragma unroll
      for (int k = 0; k < 3; ++k) eb.b[k] = ebuf[9 + k];
    }
    Aff g; compose(eb, f, g);
#pragma unroll
    for (int k = 0; k < 9; ++k) sg[s][k] = g.A[k];
#pragma unroll
    for (int k = 0; k < 3; ++k) sg[s][9 + k] = g.b[k];
  }
  __syncthreads();

  // ---- phase B: chain-split tree on all 16 waves ----
  float R[9];
#pragma unroll
  for (int k = 0; k < 9; ++k) R[k] = sg[tl][k];
  float px = sg[tl][9], py = sg[tl][10], pz = sg[tl][11];

  float M[9], ra[9], rb[9];
  if (y == 0) {                    // stores 0,1,4,7,10
    ob[0] = px; ob[1] = py; ob[2] = pz;
    float p1x, p1y, p1z, p4x, p4y, p4z, p7x, p7y, p7z, dx, dy, dz;
    childp(R, offs, 1, px, py, pz, p1x, p1y, p1z, ob);     // rots[1]=R
    childp(R, offs, 4, p1x, p1y, p1z, p4x, p4y, p4z, ob);  // parent 1, rot R
    rowmat(w0, M); mat_mul(R, M, ra);                      // r4
    childp(ra, offs, 7, p4x, p4y, p4z, p7x, p7y, p7z, ob);
    rowmat(w1, M); mat_mul(ra, M, rb);                     // r7
    childp(rb, offs, 10, p7x, p7y, p7z, dx, dy, dz, ob);
  } else if (y == 1) {             // stores 2,5,8,11
    float p2x, p2y, p2z, p5x, p5y, p5z, p8x, p8y, p8z, dx, dy, dz;
    childp(R, offs, 2, px, py, pz, p2x, p2y, p2z, ob);
    rowmat(w0, M); mat_mul(R, M, ra);                      // r2
    childp(ra, offs, 5, p2x, p2y, p2z, p5x, p5y, p5z, ob);
    rowmat(w1, M); mat_mul(ra, M, rb);                     // r5
    childp(rb, offs, 8, p5x, p5y, p5z, p8x, p8y, p8z, ob);
    rowmat(w2, M); mat_mul(rb, M, ra);                     // r8
    childp(ra, offs, 11, p8x, p8y, p8z, dx, dy, dz, ob);
  } else if (y == 2) {             // stores 3,6,9,12,15
    float p3x, p3y, p3z, p6x, p6y, p6z, p9x, p9y, p9z;
    float p12x, p12y, p12z, dx, dy, dz;
    childp(R, offs, 3, px, py, pz, p3x, p3y, p3z, ob);
    rowmat(w0, M); mat_mul(R, M, ra);                      // r3
    childp(ra, offs, 6, p3x, p3y, p3z, p6x, p6y, p6z, ob);
    rowmat(w1, M); mat_mul(ra, M, rb);                     // r6
    childp(rb, offs, 9, p6x, p6y, p6z, p9x, p9y, p9z, ob);
    rowmat(w2, M); mat_mul(rb, M, ra);                     // r9
    childp(ra, offs, 12, p9x, p9y, p9z, p12x, p12y, p12z, ob);
    rowmat(w3, M); mat_mul(ra, M, rb);                     // r12
    childp(rb, offs, 15, p12x, p12y, p12z, dx, dy, dz, ob);
  } else {                         // stores 13,16,18,20 and 14,17,19,21
    float p3x, p3y, p3z, p6x, p6y, p6z, p9x, p9y, p9z, dx, dy, dz;
    // unstored prefix to (r9, p9); rows L1-hot (chain 2 on same CU loads them)
    mat_vec(R, offs[9], offs[10], offs[11], dx, dy, dz);
    p3x = px + dx; p3y = py + dy; p3z = pz + dz;
    rowmat(w0, M); mat_mul(R, M, ra);                      // r3
    mat_vec(ra, offs[18], offs[19], offs[20], dx, dy, dz);
    p6x = p3x + dx; p6y = p3y + dy; p6z = p3z + dz;
    rowmat(w1, M); mat_mul(ra, M, rb);                     // r6
    mat_vec(rb, offs[27], offs[28], offs[29], dx, dy, dz);
    p9x = p6x + dx; p9y = p6y + dy; p9z = p6z + dz;
    rowmat(w2, M); mat_mul(rb, M, ra);                     // r9 (keep in ra)
    float r9s[9];
#pragma unroll
    for (int k = 0; k < 9; ++k) r9s[k] = ra[k];
    // branch A: 13,16,18,20
    float pAx, pAy, pAz, pBx, pBy, pBz, pCx, pCy, pCz;
    childp(r9s, offs, 13, p9x, p9y, p9z, pAx, pAy, pAz, ob);
    rowmat(w3, M); mat_mul(r9s, M, rb);                    // r13
    childp(rb, offs, 16, pAx, pAy, pAz, pBx, pBy, pBz, ob);
    rowmat(w4, M); mat_mul(rb, M, ra);                     // r16
    childp(ra, offs, 18, pBx, pBy, pBz, pCx, pCy, pCz, ob);
    rowmat(w5, M); mat_mul(ra, M, rb);                     // r18
    childp(rb, offs, 20, pCx, pCy, pCz, dx, dy, dz, ob);
    // branch B: 14,17,19,21
    childp(r9s, offs, 14, p9x, p9y, p9z, pAx, pAy, pAz, ob);
    rowmat(w6, M); mat_mul(r9s, M, rb);                    // r14
    childp(rb, offs, 17, pAx, pAy, pAz, pBx, pBy, pBz, ob);
    rowmat(w7, M); mat_mul(rb, M, ra);                     // r17
    childp(ra, offs, 19, pBx, pBy, pBz, pCx, pCy, pCz, ob);
    rowmat(w8, M); mat_mul(ra, M, rb);                     // r19
    childp(rb, offs, 21, pCx, pCy, pCz, dx, dy, dz, ob);
  }
}

extern "C" void kernel_launch(void* const* d_in, const int* in_sizes, int n_in,
                              void* d_out, int out_size, void* d_ws, size_t ws_size,
                              hipStream_t stream) {
  const float* pred = (const float*)d_in[0];   // (L, 22, 6) fp32
  const float* offs = (const float*)d_in[1];   // (22, 3)    fp32
  float* out = (float*)d_out;                  // (L, 22, 3) fp32
  float* agg = (float*)d_ws;                   // 12 * NSCB floats

  fk_agg<<<NSCB, P1B, 0, stream>>>(pred, agg);
  fk_main<<<NSCB, dim3(64, 4, 4), 0, stream>>>(pred, offs, agg, out);
}